// Round 14
// baseline (105.400 us; speedup 1.0000x reference)
//
#include <hip/hip_runtime.h>
#include <cstdint>

typedef uint16_t u16;
typedef __attribute__((ext_vector_type(8))) short short8;
typedef __attribute__((ext_vector_type(4))) float f32x4;

__device__ __forceinline__ u16 f2bf(float f) {
  uint32_t u = __float_as_uint(f);
  u += 0x7fff + ((u >> 16) & 1);   // RNE
  return (u16)(u >> 16);
}
__device__ __forceinline__ uint32_t pk2bf(float a, float b) {
  uint32_t ua = __float_as_uint(a) + 0x8000u;
  uint32_t ub = __float_as_uint(b) + 0x8000u;
  return (ua >> 16) | (ub & 0xFFFF0000u);
}

#define GLL16(gp, lp) __builtin_amdgcn_global_load_lds( \
    (__attribute__((address_space(1))) void*)(gp), \
    (__attribute__((address_space(3))) void*)(lp), 16, 0, 0)

#define SBAR()       __builtin_amdgcn_s_barrier()
#define WAIT_LGKM0() asm volatile("s_waitcnt lgkmcnt(0)" ::: "memory")
#define WAIT_VM(N)   asm volatile("s_waitcnt vmcnt(" #N ")" ::: "memory")
#define MEMBAR()     asm volatile("" ::: "memory")

// ---------------- fused f32 -> bf16 convert; Wq pre-scaled by d^-0.5 * log2(e) ----------------
__global__ void cvt_all(const float* __restrict__ x,  const float* __restrict__ wq,
                        const float* __restrict__ wk, const float* __restrict__ wv,
                        const float* __restrict__ wo,
                        u16* __restrict__ xb, u16* __restrict__ wcat, u16* __restrict__ wob) {
  int i = blockIdx.x * 256 + threadIdx.x;
  const float4* src; ushort4* dst; int off; float sc = 1.0f;
  if (i < 1048576)      { src = (const float4*)x;  dst = (ushort4*)xb;              off = i; }
  else if (i < 1310720) { src = (const float4*)wq; dst = (ushort4*)wcat;            off = i - 1048576;
                          sc = 0.18033688011112042f; }   // 0.125 * log2(e)
  else if (i < 1572864) { src = (const float4*)wk; dst = (ushort4*)wcat + 262144;   off = i - 1310720; }
  else if (i < 1835008) { src = (const float4*)wv; dst = (ushort4*)wcat + 524288;   off = i - 1572864; }
  else                  { src = (const float4*)wo; dst = (ushort4*)wob;             off = i - 1835008; }
  float4 v = src[off];
  ushort4 o;
  o.x = f2bf(v.x * sc); o.y = f2bf(v.y * sc); o.z = f2bf(v.z * sc); o.w = f2bf(v.w * sc);
  dst[off] = o;
}

// ---------------- 256x256 8-phase QKV GEMM: C[m][n] = sum_k A[m][k]*B[n][k], M=4096 N=3072 K=1024 ----
// 512 thr = 8 waves (2M x 4N); wave output 128x64 = acc[8][4]. BK=64, 16 K-tiles, 2 tiles/iter.
// Balanced quadrant phases: P1 reads a0-3+b0-1 (12), P2 a4-7 (8), P3 b2-3 (4), P4 none.
// Stage slots (region-exact): P1:(T+1).B0 P2:(T+1).B1 P3:(T+2).A0 P4:(T+2).A1
//                             P5:(T+2).B0 P6:(T+2).B1 P7:(T+3).A0 P8:(T+3).A1
// Counted vmcnt(4) at P4/P8 (2 stages issued after the awaited tile's newest half); i==7 -> vmcnt(0).
__global__ __launch_bounds__(512, 1) void gemm256(const u16* __restrict__ A,
                                                  const u16* __restrict__ B,
                                                  u16* __restrict__ Cp) {
  __shared__ u16 sm[2][2][256 * 64];   // [buf][A,B][row*64+k], rows 128B, XOR swizzle (row&7)<<4
  const int tid  = threadIdx.x;
  const int lane = tid & 63, w = tid >> 6;
  const int wr = w >> 2, wc = w & 3;
  const int g = lane >> 4, lr = lane & 15;

  const int id = blockIdx.x;                 // 192 blocks, 192 % 8 == 0
  const int sw = (id & 7) * 24 + (id >> 3);  // XCD-aware bijective swizzle
  const int row0 = (sw % 16) * 256;
  const int col0 = (sw / 16) * 256;

  f32x4 acc[8][4];
  #pragma unroll
  for (int m = 0; m < 8; ++m)
    #pragma unroll
    for (int n = 0; n < 4; ++n) acc[m][n] = (f32x4){0.f, 0.f, 0.f, 0.f};

  // stage one 128x64 half-tile (2 GLL16 x 512 thr = 16 KB); buf = kt parity
  auto STAGE = [&](int kt, int ab, int half) {
    if (kt >= 16) return;
    const u16* __restrict__ src = ab ? B : A;
    const int rb = (ab ? col0 : row0) + half * 128;
    u16* lds = &sm[kt & 1][ab][half * 128 * 64];
    #pragma unroll
    for (int j = 0; j < 2; ++j) {
      int r  = j * 64 + w * 8 + (lane >> 3);
      int sb = ((lane & 7) << 4) ^ ((r & 7) << 4);
      GLL16(src + (size_t)(rb + r) * 1024 + kt * 64 + (sb >> 1),
            lds + (size_t)(j * 512 + w * 64) * 8);
    }
  };

  short8 a[8][2], b[4][2];
  auto RDA = [&](int buf, int m0) {
    #pragma unroll
    for (int mm = 0; mm < 4; ++mm)
      #pragma unroll
      for (int kh = 0; kh < 2; ++kh) {
        int row = wr * 128 + (m0 + mm) * 16 + lr;
        int col = (kh * 64 + g * 16) ^ ((row & 7) << 4);
        a[m0 + mm][kh] = *(const short8*)((const char*)&sm[buf][0][0] + row * 128 + col);
      }
  };
  auto RDB = [&](int buf, int n0) {
    #pragma unroll
    for (int nn = 0; nn < 2; ++nn)
      #pragma unroll
      for (int kh = 0; kh < 2; ++kh) {
        int row = wc * 64 + (n0 + nn) * 16 + lr;
        int col = (kh * 64 + g * 16) ^ ((row & 7) << 4);
        b[n0 + nn][kh] = *(const short8*)((const char*)&sm[buf][1][0] + row * 128 + col);
      }
  };
  auto QUAD = [&](int m0, int n0) {   // 16 MFMA, kh-outer (dep distance 8)
    __builtin_amdgcn_s_setprio(1);
    #pragma unroll
    for (int kh = 0; kh < 2; ++kh)
      #pragma unroll
      for (int mm = 0; mm < 4; ++mm)
        #pragma unroll
        for (int nn = 0; nn < 2; ++nn)
          acc[m0 + mm][n0 + nn] = __builtin_amdgcn_mfma_f32_16x16x32_bf16(
              a[m0 + mm][kh], b[n0 + nn][kh], acc[m0 + mm][n0 + nn], 0, 0, 0);
    __builtin_amdgcn_s_setprio(0);
  };

  // prologue: T0 all 4 halves + T1.A0,A1 (T1.B0/B1 staged at P1/P2)
  STAGE(0, 0, 0); STAGE(0, 0, 1); STAGE(0, 1, 0); STAGE(0, 1, 1);
  STAGE(1, 0, 0); STAGE(1, 0, 1);
  WAIT_VM(4); SBAR(); MEMBAR();

  for (int i = 0; i < 8; ++i) {
    const int T = 2 * i;
    // ---- P1 (tile T, buf0) ----
    RDA(0, 0); RDB(0, 0); STAGE(T + 1, 1, 0); MEMBAR();
    SBAR(); WAIT_LGKM0(); MEMBAR();
    QUAD(0, 0);
    MEMBAR(); SBAR(); MEMBAR();
    // ---- P2 ----
    RDA(0, 4); STAGE(T + 1, 1, 1); MEMBAR();
    SBAR(); WAIT_LGKM0(); MEMBAR();
    QUAD(4, 0);
    MEMBAR(); SBAR(); MEMBAR();
    // ---- P3 ----
    RDB(0, 2); STAGE(T + 2, 0, 0); MEMBAR();
    SBAR(); WAIT_LGKM0(); MEMBAR();
    QUAD(0, 2);
    MEMBAR(); SBAR(); MEMBAR();
    // ---- P4 + checkpoint (tile T+1 landed) ----
    STAGE(T + 2, 0, 1); MEMBAR();
    SBAR(); MEMBAR();
    QUAD(4, 2);
    if (i == 7) { WAIT_VM(0); } else { WAIT_VM(4); }
    MEMBAR(); SBAR(); MEMBAR();
    // ---- P5 (tile T+1, buf1) ----
    RDA(1, 0); RDB(1, 0); STAGE(T + 2, 1, 0); MEMBAR();
    SBAR(); WAIT_LGKM0(); MEMBAR();
    QUAD(0, 0);
    MEMBAR(); SBAR(); MEMBAR();
    // ---- P6 ----
    RDA(1, 4); STAGE(T + 2, 1, 1); MEMBAR();
    SBAR(); WAIT_LGKM0(); MEMBAR();
    QUAD(4, 0);
    MEMBAR(); SBAR(); MEMBAR();
    // ---- P7 ----
    RDB(1, 2); STAGE(T + 3, 0, 0); MEMBAR();
    SBAR(); WAIT_LGKM0(); MEMBAR();
    QUAD(0, 2);
    MEMBAR(); SBAR(); MEMBAR();
    // ---- P8 + checkpoint (tile T+2 landed) ----
    STAGE(T + 3, 0, 1); MEMBAR();
    SBAR(); MEMBAR();
    QUAD(4, 2);
    if (i == 7) { WAIT_VM(0); } else { WAIT_VM(4); }
    MEMBAR(); SBAR(); MEMBAR();
  }

  // epilogue
  #pragma unroll
  for (int m = 0; m < 8; ++m)
    #pragma unroll
    for (int n = 0; n < 4; ++n)
      #pragma unroll
      for (int ri = 0; ri < 4; ++ri) {
        int rr = row0 + wr * 128 + m * 16 + g * 4 + ri;
        int cc = col0 + wc * 64 + n * 16 + lr;
        Cp[(size_t)rr * 3072 + cc] = f2bf(acc[m][n][ri]);
      }
}

// ---------------- BMx128 counted-vmcnt GEMM (proj: BM=64, OCC=2, 512 blocks) ----------------
template<int BM, int OUT_BF16, int OCC>
__global__ __launch_bounds__(256, OCC) void gemm_t(const u16* __restrict__ A,
                                                   const u16* __restrict__ B,
                                                   void* __restrict__ Cout,
                                                   int N, int K, int ntN) {
  constexpr int MF = BM / 32;
  __shared__ u16 smA[2][BM * 64];
  __shared__ u16 smB[2][128 * 64];
  const int tid  = threadIdx.x;
  const int lane = tid & 63, w = tid >> 6;
  const int wr = w >> 1, wc = w & 1;
  const int g = lane >> 4, lr = lane & 15;

  const int cpx = gridDim.x >> 3;
  const int id  = blockIdx.x;
  const int sw  = (id & 7) * cpx + (id >> 3);
  const int row0 = (sw / ntN) * BM, col0 = (sw % ntN) * 128;
  const int T = K >> 6;

  f32x4 acc[MF][4];
  #pragma unroll
  for (int i = 0; i < MF; ++i)
    #pragma unroll
    for (int j = 0; j < 4; ++j) acc[i][j] = (f32x4){0.f, 0.f, 0.f, 0.f};

  auto STAGE = [&](int kt, int bufi) {
    #pragma unroll
    for (int j = 0; j < BM / 32; ++j) {
      int r  = j * 32 + w * 8 + (lane >> 3);
      int sb = ((lane & 7) << 4) ^ ((r & 7) << 4);
      GLL16(A + (size_t)(row0 + r) * K + kt * 64 + (sb >> 1),
            &smA[bufi][(size_t)(j * 32 + w * 8) * 64]);
    }
    #pragma unroll
    for (int j = 0; j < 4; ++j) {
      int r  = j * 32 + w * 8 + (lane >> 3);
      int sb = ((lane & 7) << 4) ^ ((r & 7) << 4);
      GLL16(B + (size_t)(col0 + r) * K + kt * 64 + (sb >> 1),
            &smB[bufi][(size_t)(j * 32 + w * 8) * 64]);
    }
  };
  auto WVM_STEADY = [&]() {
    if constexpr (BM == 128) { WAIT_VM(8); } else { WAIT_VM(6); }
  };

  STAGE(0, 0); STAGE(1, 1);
  WVM_STEADY(); SBAR(); MEMBAR();

  for (int t = 0; t < T; ++t) {
    const int cur = t & 1;
    short8 a[MF][2], b[4][2];
    #pragma unroll
    for (int mm = 0; mm < MF; ++mm)
      #pragma unroll
      for (int kh = 0; kh < 2; ++kh) {
        int row = wr * (BM / 2) + mm * 16 + lr;
        int col = (kh * 64 + g * 16) ^ ((row & 7) << 4);
        a[mm][kh] = *(const short8*)((const char*)&smA[cur][0] + row * 128 + col);
      }
    #pragma unroll
    for (int nn = 0; nn < 4; ++nn)
      #pragma unroll
      for (int kh = 0; kh < 2; ++kh) {
        int row = wc * 64 + nn * 16 + lr;
        int col = (kh * 64 + g * 16) ^ ((row & 7) << 4);
        b[nn][kh] = *(const short8*)((const char*)&smB[cur][0] + row * 128 + col);
      }
    WAIT_LGKM0(); MEMBAR(); SBAR(); MEMBAR();

    if (t + 2 < T) STAGE(t + 2, cur);

    __builtin_amdgcn_s_setprio(1);
    #pragma unroll
    for (int kh = 0; kh < 2; ++kh)
      #pragma unroll
      for (int mm = 0; mm < MF; ++mm)
        #pragma unroll
        for (int nn = 0; nn < 4; ++nn)
          acc[mm][nn] = __builtin_amdgcn_mfma_f32_16x16x32_bf16(
              a[mm][kh], b[nn][kh], acc[mm][nn], 0, 0, 0);
    __builtin_amdgcn_s_setprio(0);

    if (t + 1 < T) {
      if (t + 2 < T) { WVM_STEADY(); } else { WAIT_VM(0); }
      SBAR(); MEMBAR();
    }
  }

  #pragma unroll
  for (int i = 0; i < MF; ++i)
    #pragma unroll
    for (int j = 0; j < 4; ++j)
      #pragma unroll
      for (int ri = 0; ri < 4; ++ri) {
        int rr = row0 + wr * (BM / 2) + i * 16 + g * 4 + ri;
        int cc = col0 + wc * 64 + j * 16 + lr;
        if (OUT_BF16) ((u16*)Cout)[(size_t)rr * N + cc] = f2bf(acc[i][j][ri]);
        else          ((float*)Cout)[(size_t)rr * N + cc] = acc[i][j][ri];
      }
}

// ---------------- Flash sliding-window attention (v8, unchanged from round 12) ----------------
__global__ __launch_bounds__(256, 3) void attn_swa(const u16* __restrict__ QKV, u16* __restrict__ O) {
  const int S = 2048;
  const int qb = blockIdx.x * 128;
  const int b = blockIdx.y >> 4, h = blockIdx.y & 15;
  const int tid = threadIdx.x;
  const int lane = tid & 63, w = tid >> 6;
  const int g = lane >> 4, lr = lane & 15;

  __shared__ u16 Klds[2][64 * 64];
  __shared__ u16 Vt[2][64][72];
  __shared__ u16 Plds[4][32][72];

  const u16* Qb = QKV + (size_t)b * S * 3072 + h * 64;
  const u16* Kb = QKV + (size_t)b * S * 3072 + 1024 + h * 64;
  const u16* Vb = QKV + (size_t)b * S * 3072 + 2048 + h * 64;

  const int qw = qb + w * 32;
  short8 qf[2][2];
  #pragma unroll
  for (int qg = 0; qg < 2; ++qg)
    #pragma unroll
    for (int kh = 0; kh < 2; ++kh)
      qf[qg][kh] = *(const short8*)(Qb + (size_t)(qw + qg * 16 + lr) * 3072 + kh * 32 + g * 8);

  float ls[2] = {0.f, 0.f};
  f32x4 accO[2][4];
  #pragma unroll
  for (int qg = 0; qg < 2; ++qg)
    #pragma unroll
    for (int i = 0; i < 4; ++i) accO[qg][i] = (f32x4){0.f, 0.f, 0.f, 0.f};

  int ks = qb - 511; if (ks < 0) ks = 0; ks &= ~63;
  const int ke = qb + 127;
  const int nt = ((ke - ks) >> 6) + 1;

  short8 vreg0, vreg1;

  auto STAGE_K = [&](int kb, int buf) {
    #pragma unroll
    for (int c = 0; c < 2; ++c) {
      int r  = c * 32 + w * 8 + (lane >> 3);
      int sb = ((lane & 7) << 4) ^ ((r & 7) << 4);
      const u16* gp = Kb + (size_t)(kb + r) * 3072 + (sb >> 1);
      u16* lp = Klds[buf] + c * 2048 + w * 512;
      GLL16(gp, lp);
    }
  };
  auto LOAD_V = [&](int kb) {
    vreg0 = *(const short8*)(Vb + (size_t)(kb + lane) * 3072 + w * 8);
    vreg1 = *(const short8*)(Vb + (size_t)(kb + lane) * 3072 + w * 8 + 32);
  };
  auto WRITE_V = [&](int buf) {
    #pragma unroll
    for (int j = 0; j < 8; ++j) Vt[buf][w * 8 + j][lane]      = (u16)vreg0[j];
    #pragma unroll
    for (int j = 0; j < 8; ++j) Vt[buf][w * 8 + 32 + j][lane] = (u16)vreg1[j];
  };

  LOAD_V(ks); MEMBAR();
  STAGE_K(ks, 0); MEMBAR();
  WAIT_VM(0); MEMBAR();
  SBAR(); MEMBAR();
  WRITE_V(0);

  int cur = 0, kb = ks;
  for (int t = 0; t < nt; ++t, kb += 64) {
    const int nxt = cur ^ 1;
    const bool more = (t + 1 < nt);
    if (more) { LOAD_V(kb + 64); MEMBAR(); STAGE_K(kb + 64, nxt); MEMBAR(); }

    const bool active = (kb <= qw + 31) && (kb + 63 >= qw - 511);
    if (active) {
      float p[2][4][4];
      #pragma unroll
      for (int st = 0; st < 4; ++st) {
        f32x4 c4[2];
        c4[0] = (f32x4){0.f, 0.f, 0.f, 0.f};
        c4[1] = (f32x4){0.f, 0.f, 0.f, 0.f};
        int r = st * 16 + lr;
        int swz = (r & 7) << 4;
        const char* krow = (const char*)(Klds[cur]) + r * 128;
        short8 kf0 = *(const short8*)(krow + ((g * 16) ^ swz));
        short8 kf1 = *(const short8*)(krow + ((64 + g * 16) ^ swz));
        __builtin_amdgcn_s_setprio(1);
        c4[0] = __builtin_amdgcn_mfma_f32_16x16x32_bf16(kf0, qf[0][0], c4[0], 0, 0, 0);
        c4[1] = __builtin_amdgcn_mfma_f32_16x16x32_bf16(kf0, qf[1][0], c4[1], 0, 0, 0);
        c4[0] = __builtin_amdgcn_mfma_f32_16x16x32_bf16(kf1, qf[0][1], c4[0], 0, 0, 0);
        c4[1] = __builtin_amdgcn_mfma_f32_16x16x32_bf16(kf1, qf[1][1], c4[1], 0, 0, 0);
        __builtin_amdgcn_s_setprio(0);
        #pragma unroll
        for (int ri = 0; ri < 4; ++ri) { p[0][st][ri] = c4[0][ri]; p[1][st][ri] = c4[1][ri]; }
      }

      #pragma unroll
      for (int qg = 0; qg < 2; ++qg) {
        const int q0 = qw + qg * 16;
        const bool clean = (kb + 63 <= q0) && (q0 + 15 - kb < 512);
        if (clean) {
          #pragma unroll
          for (int st = 0; st < 4; ++st)
            #pragma unroll
            for (int ri = 0; ri < 4; ++ri)
              p[qg][st][ri] = __builtin_amdgcn_exp2f(p[qg][st][ri]);
        } else {
          const int base = q0 + lr - kb;
          #pragma unroll
          for (int st = 0; st < 4; ++st)
            #pragma unroll
            for (int ri = 0; ri < 4; ++ri) {
              float e = __builtin_amdgcn_exp2f(p[qg][st][ri]);
              p[qg][st][ri] = ((uint32_t)(base - (st * 16 + g * 4 + ri)) < 512u) ? e : 0.f;
            }
        }
        float s = 0.f;
        #pragma unroll
        for (int st = 0; st < 4; ++st)
          #pragma unroll
          for (int ri = 0; ri < 4; ++ri) s += p[qg][st][ri];
        s += __shfl_xor(s, 16);
        s += __shfl_xor(s, 32);
        ls[qg] += s;

        #pragma unroll
        for (int st = 0; st < 4; ++st) {
          uint2 u2;
          u2.x = pk2bf(p[qg][st][0], p[qg][st][1]);
          u2.y = pk2bf(p[qg][st][2], p[qg][st][3]);
          *(uint2*)(&Plds[w][qg * 16 + lr][st * 16 + g * 4]) = u2;
        }
      }
    }

    if (more) { WAIT_VM(0); MEMBAR(); }
    WAIT_LGKM0(); MEMBAR();
    SBAR(); MEMBAR();
    if (more) WRITE_V(nxt);

    if (active) {
      short8 pf[2][2];
      #pragma unroll
      for (int qg = 0; qg < 2; ++qg) {
        pf[qg][0] = *(const short8*)(&Plds[w][qg * 16 + lr][g * 8]);
        pf[qg][1] = *(const short8*)(&Plds[w][qg * 16 + lr][32 + g * 8]);
      }
      __builtin_amdgcn_s_setprio(1);
      #pragma unroll
      for (int dt = 0; dt < 4; ++dt) {
        short8 vf0 = *(const short8*)(&Vt[cur][dt * 16 + lr][g * 8]);
        short8 vf1 = *(const short8*)(&Vt[cur][dt * 16 + lr][32 + g * 8]);
        accO[0][dt] = __builtin_amdgcn_mfma_f32_16x16x32_bf16(pf[0][0], vf0, accO[0][dt], 0, 0, 0);
        accO[1][dt] = __builtin_amdgcn_mfma_f32_16x16x32_bf16(pf[1][0], vf0, accO[1][dt], 0, 0, 0);
        accO[0][dt] = __builtin_amdgcn_mfma_f32_16x16x32_bf16(pf[0][1], vf1, accO[0][dt], 0, 0, 0);
        accO[1][dt] = __builtin_amdgcn_mfma_f32_16x16x32_bf16(pf[1][1], vf1, accO[1][dt], 0, 0, 0);
      }
      __builtin_amdgcn_s_setprio(0);
    }
    cur = nxt;
  }

  #pragma unroll
  for (int qg = 0; qg < 2; ++qg) {
    float lsq[4];
    #pragma unroll
    for (int ri = 0; ri < 4; ++ri) lsq[ri] = __shfl(ls[qg], g * 4 + ri);
    #pragma unroll
    for (int dt = 0; dt < 4; ++dt)
      #pragma unroll
      for (int ri = 0; ri < 4; ++ri) {
        int qi = qw + qg * 16 + g * 4 + ri;
        O[(size_t)(b * S + qi) * 1024 + h * 64 + dt * 16 + lr] = f2bf(accO[qg][dt][ri] / lsq[ri]);
      }
  }
}

// ---------------- launch ----------------
extern "C" void kernel_launch(void* const* d_in, const int* in_sizes, int n_in,
                              void* d_out, int out_size, void* d_ws, size_t ws_size,
                              hipStream_t stream) {
  const float* x  = (const float*)d_in[0];
  const float* Wq = (const float*)d_in[1];
  const float* Wk = (const float*)d_in[2];
  const float* Wv = (const float*)d_in[3];
  const float* Wo = (const float*)d_in[4];

  char* ws = (char*)d_ws;
  u16* xb   = (u16*)(ws);                    //  8 MiB: x bf16 [4096][1024]
  u16* Wcat = (u16*)(ws + (8  << 20));       //  6 MiB: [Wq;Wk;Wv] bf16 [3072][1024]
  u16* Wob  = (u16*)(ws + (14 << 20));       //  2 MiB: Wo bf16 [1024][1024]
  u16* QKV  = (u16*)(ws + (16 << 20));       // 24 MiB: [4096][3072]
  u16* Oatt = (u16*)(ws + (40 << 20));       //  8 MiB: [4096][1024]

  cvt_all<<<8192, 256, 0, stream>>>(x, Wq, Wk, Wv, Wo, xb, Wcat, Wob);
  gemm256<<<192, 512, 0, stream>>>(xb, Wcat, QKV);
  attn_swa<<<dim3(16, 32), 256, 0, stream>>>(QKV, Oatt);
  gemm_t<64, 0, 2><<<512, 256, 0, stream>>>(Oatt, Wob, d_out, 1024, 1024, 8);
}

// Round 16
// 83.828 us; speedup vs baseline: 1.2573x; 1.2573x over previous
//
#include <hip/hip_runtime.h>
#include <cstdint>

typedef uint16_t u16;
typedef __attribute__((ext_vector_type(8))) short short8;
typedef __attribute__((ext_vector_type(4))) float f32x4;

__device__ __forceinline__ u16 f2bf(float f) {
  uint32_t u = __float_as_uint(f);
  u += 0x7fff + ((u >> 16) & 1);   // RNE
  return (u16)(u >> 16);
}
__device__ __forceinline__ uint32_t pk2bf(float a, float b) {
  uint32_t ua = __float_as_uint(a) + 0x8000u;
  uint32_t ub = __float_as_uint(b) + 0x8000u;
  return (ua >> 16) | (ub & 0xFFFF0000u);
}

#define GLL16(gp, lp) __builtin_amdgcn_global_load_lds( \
    (__attribute__((address_space(1))) void*)(gp), \
    (__attribute__((address_space(3))) void*)(lp), 16, 0, 0)

#define SBAR()       __builtin_amdgcn_s_barrier()
#define WAIT_LGKM0() asm volatile("s_waitcnt lgkmcnt(0)" ::: "memory")
#define WAIT_VM(N)   asm volatile("s_waitcnt vmcnt(" #N ")" ::: "memory")
#define MEMBAR()     asm volatile("" ::: "memory")

// vmcnt immediate must be a literal in the asm string -> if constexpr dispatch
template<int N> __device__ __forceinline__ void wait_vm() {
  static_assert(N == 0 || N == 4 || N == 6 || N == 8 || N == 10 || N == 12, "add literal case");
  if constexpr (N == 0)  { WAIT_VM(0); }
  else if constexpr (N == 4)  { WAIT_VM(4); }
  else if constexpr (N == 6)  { WAIT_VM(6); }
  else if constexpr (N == 8)  { WAIT_VM(8); }
  else if constexpr (N == 10) { WAIT_VM(10); }
  else if constexpr (N == 12) { WAIT_VM(12); }
}

// ---------------- fused f32 -> bf16 convert; Wq pre-scaled by d^-0.5 * log2(e) ----------------
__global__ void cvt_all(const float* __restrict__ x,  const float* __restrict__ wq,
                        const float* __restrict__ wk, const float* __restrict__ wv,
                        const float* __restrict__ wo,
                        u16* __restrict__ xb, u16* __restrict__ wcat, u16* __restrict__ wob) {
  int i = blockIdx.x * 256 + threadIdx.x;
  const float4* src; ushort4* dst; int off; float sc = 1.0f;
  if (i < 1048576)      { src = (const float4*)x;  dst = (ushort4*)xb;              off = i; }
  else if (i < 1310720) { src = (const float4*)wq; dst = (ushort4*)wcat;            off = i - 1048576;
                          sc = 0.18033688011112042f; }   // 0.125 * log2(e)
  else if (i < 1572864) { src = (const float4*)wk; dst = (ushort4*)wcat + 262144;   off = i - 1310720; }
  else if (i < 1835008) { src = (const float4*)wv; dst = (ushort4*)wcat + 524288;   off = i - 1572864; }
  else                  { src = (const float4*)wo; dst = (ushort4*)wob;             off = i - 1835008; }
  float4 v = src[off];
  ushort4 o;
  o.x = f2bf(v.x * sc); o.y = f2bf(v.y * sc); o.z = f2bf(v.z * sc); o.w = f2bf(v.w * sc);
  dst[off] = o;
}

// ---------------- BMxBN counted-vmcnt GEMM: C[m][n] = sum_k A[m][k]*B[n][k] ----------------
// 4 waves (2x2): wave tile (BM/2)x(BN/2). BK=64 double-buffered, XOR swizzle (row&7)<<4
// via pre-swizzled GLL source. Steady state: stage t+2 during t, counted wait_vm<G>() where
// G = (BM+BN)/32 GLLs per wave per tile. QKV: 128x192 -> 512 blocks = exactly 2/CU, LDS
// 80 KB. Proj: 64x128 -> 512 blocks, LDS 48 KB.
template<int BM, int BN, int OUT_BF16>
__global__ __launch_bounds__(256, 2) void gemm_t(const u16* __restrict__ A,
                                                 const u16* __restrict__ B,
                                                 void* __restrict__ Cout,
                                                 int N, int K, int ntN) {
  constexpr int MF = BM / 32;          // m-frags per wave
  constexpr int NF = BN / 32;          // n-frags per wave
  constexpr int G  = (BM + BN) / 32;   // GLLs per wave per tile stage
  __shared__ u16 smA[2][BM * 64];
  __shared__ u16 smB[2][BN * 64];
  const int tid  = threadIdx.x;
  const int lane = tid & 63, w = tid >> 6;
  const int wr = w >> 1, wc = w & 1;
  const int g = lane >> 4, lr = lane & 15;

  const int cpx = gridDim.x >> 3;
  const int id  = blockIdx.x;
  const int sw  = (id & 7) * cpx + (id >> 3);
  const int row0 = (sw / ntN) * BM, col0 = (sw % ntN) * BN;
  const int T = K >> 6;

  f32x4 acc[MF][NF];
  #pragma unroll
  for (int i = 0; i < MF; ++i)
    #pragma unroll
    for (int j = 0; j < NF; ++j) acc[i][j] = (f32x4){0.f, 0.f, 0.f, 0.f};

  auto STAGE = [&](int kt, int bufi) {
    #pragma unroll
    for (int j = 0; j < BM / 32; ++j) {
      int r  = j * 32 + w * 8 + (lane >> 3);
      int sb = ((lane & 7) << 4) ^ ((r & 7) << 4);
      GLL16(A + (size_t)(row0 + r) * K + kt * 64 + (sb >> 1),
            &smA[bufi][(size_t)(j * 32 + w * 8) * 64]);
    }
    #pragma unroll
    for (int j = 0; j < BN / 32; ++j) {
      int r  = j * 32 + w * 8 + (lane >> 3);
      int sb = ((lane & 7) << 4) ^ ((r & 7) << 4);
      GLL16(B + (size_t)(col0 + r) * K + kt * 64 + (sb >> 1),
            &smB[bufi][(size_t)(j * 32 + w * 8) * 64]);
    }
  };

  STAGE(0, 0); STAGE(1, 1);
  wait_vm<G>(); SBAR(); MEMBAR();

  for (int t = 0; t < T; ++t) {
    const int cur = t & 1;
    short8 a[MF][2], b[NF][2];
    #pragma unroll
    for (int mm = 0; mm < MF; ++mm)
      #pragma unroll
      for (int kh = 0; kh < 2; ++kh) {
        int row = wr * (BM / 2) + mm * 16 + lr;
        int col = (kh * 64 + g * 16) ^ ((row & 7) << 4);
        a[mm][kh] = *(const short8*)((const char*)&smA[cur][0] + row * 128 + col);
      }
    #pragma unroll
    for (int nn = 0; nn < NF; ++nn)
      #pragma unroll
      for (int kh = 0; kh < 2; ++kh) {
        int row = wc * (BN / 2) + nn * 16 + lr;
        int col = (kh * 64 + g * 16) ^ ((row & 7) << 4);
        b[nn][kh] = *(const short8*)((const char*)&smB[cur][0] + row * 128 + col);
      }
    WAIT_LGKM0(); MEMBAR(); SBAR(); MEMBAR();   // all waves' reads of buf[cur] done

    if (t + 2 < T) STAGE(t + 2, cur);

    __builtin_amdgcn_s_setprio(1);
    #pragma unroll
    for (int kh = 0; kh < 2; ++kh)
      #pragma unroll
      for (int mm = 0; mm < MF; ++mm)
        #pragma unroll
        for (int nn = 0; nn < NF; ++nn)
          acc[mm][nn] = __builtin_amdgcn_mfma_f32_16x16x32_bf16(
              a[mm][kh], b[nn][kh], acc[mm][nn], 0, 0, 0);
    __builtin_amdgcn_s_setprio(0);

    if (t + 1 < T) {
      if (t + 2 < T) { wait_vm<G>(); } else { wait_vm<0>(); }
      SBAR(); MEMBAR();
    }
  }

  #pragma unroll
  for (int i = 0; i < MF; ++i)
    #pragma unroll
    for (int j = 0; j < NF; ++j)
      #pragma unroll
      for (int ri = 0; ri < 4; ++ri) {
        int rr = row0 + wr * (BM / 2) + i * 16 + g * 4 + ri;
        int cc = col0 + wc * (BN / 2) + j * 16 + lr;
        if (OUT_BF16) ((u16*)Cout)[(size_t)rr * N + cc] = f2bf(acc[i][j][ri]);
        else          ((float*)Cout)[(size_t)rr * N + cc] = acc[i][j][ri];
      }
}

// ---------------- Flash sliding-window attention (v8, unchanged from round 12) ----------------
__global__ __launch_bounds__(256, 3) void attn_swa(const u16* __restrict__ QKV, u16* __restrict__ O) {
  const int S = 2048;
  const int qb = blockIdx.x * 128;
  const int b = blockIdx.y >> 4, h = blockIdx.y & 15;
  const int tid = threadIdx.x;
  const int lane = tid & 63, w = tid >> 6;
  const int g = lane >> 4, lr = lane & 15;

  __shared__ u16 Klds[2][64 * 64];
  __shared__ u16 Vt[2][64][72];
  __shared__ u16 Plds[4][32][72];

  const u16* Qb = QKV + (size_t)b * S * 3072 + h * 64;
  const u16* Kb = QKV + (size_t)b * S * 3072 + 1024 + h * 64;
  const u16* Vb = QKV + (size_t)b * S * 3072 + 2048 + h * 64;

  const int qw = qb + w * 32;
  short8 qf[2][2];
  #pragma unroll
  for (int qg = 0; qg < 2; ++qg)
    #pragma unroll
    for (int kh = 0; kh < 2; ++kh)
      qf[qg][kh] = *(const short8*)(Qb + (size_t)(qw + qg * 16 + lr) * 3072 + kh * 32 + g * 8);

  float ls[2] = {0.f, 0.f};
  f32x4 accO[2][4];
  #pragma unroll
  for (int qg = 0; qg < 2; ++qg)
    #pragma unroll
    for (int i = 0; i < 4; ++i) accO[qg][i] = (f32x4){0.f, 0.f, 0.f, 0.f};

  int ks = qb - 511; if (ks < 0) ks = 0; ks &= ~63;
  const int ke = qb + 127;
  const int nt = ((ke - ks) >> 6) + 1;

  short8 vreg0, vreg1;

  auto STAGE_K = [&](int kb, int buf) {
    #pragma unroll
    for (int c = 0; c < 2; ++c) {
      int r  = c * 32 + w * 8 + (lane >> 3);
      int sb = ((lane & 7) << 4) ^ ((r & 7) << 4);
      const u16* gp = Kb + (size_t)(kb + r) * 3072 + (sb >> 1);
      u16* lp = Klds[buf] + c * 2048 + w * 512;
      GLL16(gp, lp);
    }
  };
  auto LOAD_V = [&](int kb) {
    vreg0 = *(const short8*)(Vb + (size_t)(kb + lane) * 3072 + w * 8);
    vreg1 = *(const short8*)(Vb + (size_t)(kb + lane) * 3072 + w * 8 + 32);
  };
  auto WRITE_V = [&](int buf) {
    #pragma unroll
    for (int j = 0; j < 8; ++j) Vt[buf][w * 8 + j][lane]      = (u16)vreg0[j];
    #pragma unroll
    for (int j = 0; j < 8; ++j) Vt[buf][w * 8 + 32 + j][lane] = (u16)vreg1[j];
  };

  LOAD_V(ks); MEMBAR();
  STAGE_K(ks, 0); MEMBAR();
  WAIT_VM(0); MEMBAR();
  SBAR(); MEMBAR();
  WRITE_V(0);

  int cur = 0, kb = ks;
  for (int t = 0; t < nt; ++t, kb += 64) {
    const int nxt = cur ^ 1;
    const bool more = (t + 1 < nt);
    if (more) { LOAD_V(kb + 64); MEMBAR(); STAGE_K(kb + 64, nxt); MEMBAR(); }

    const bool active = (kb <= qw + 31) && (kb + 63 >= qw - 511);
    if (active) {
      float p[2][4][4];
      #pragma unroll
      for (int st = 0; st < 4; ++st) {
        f32x4 c4[2];
        c4[0] = (f32x4){0.f, 0.f, 0.f, 0.f};
        c4[1] = (f32x4){0.f, 0.f, 0.f, 0.f};
        int r = st * 16 + lr;
        int swz = (r & 7) << 4;
        const char* krow = (const char*)(Klds[cur]) + r * 128;
        short8 kf0 = *(const short8*)(krow + ((g * 16) ^ swz));
        short8 kf1 = *(const short8*)(krow + ((64 + g * 16) ^ swz));
        __builtin_amdgcn_s_setprio(1);
        c4[0] = __builtin_amdgcn_mfma_f32_16x16x32_bf16(kf0, qf[0][0], c4[0], 0, 0, 0);
        c4[1] = __builtin_amdgcn_mfma_f32_16x16x32_bf16(kf0, qf[1][0], c4[1], 0, 0, 0);
        c4[0] = __builtin_amdgcn_mfma_f32_16x16x32_bf16(kf1, qf[0][1], c4[0], 0, 0, 0);
        c4[1] = __builtin_amdgcn_mfma_f32_16x16x32_bf16(kf1, qf[1][1], c4[1], 0, 0, 0);
        __builtin_amdgcn_s_setprio(0);
        #pragma unroll
        for (int ri = 0; ri < 4; ++ri) { p[0][st][ri] = c4[0][ri]; p[1][st][ri] = c4[1][ri]; }
      }

      #pragma unroll
      for (int qg = 0; qg < 2; ++qg) {
        const int q0 = qw + qg * 16;
        const bool clean = (kb + 63 <= q0) && (q0 + 15 - kb < 512);
        if (clean) {
          #pragma unroll
          for (int st = 0; st < 4; ++st)
            #pragma unroll
            for (int ri = 0; ri < 4; ++ri)
              p[qg][st][ri] = __builtin_amdgcn_exp2f(p[qg][st][ri]);
        } else {
          const int base = q0 + lr - kb;
          #pragma unroll
          for (int st = 0; st < 4; ++st)
            #pragma unroll
            for (int ri = 0; ri < 4; ++ri) {
              float e = __builtin_amdgcn_exp2f(p[qg][st][ri]);
              p[qg][st][ri] = ((uint32_t)(base - (st * 16 + g * 4 + ri)) < 512u) ? e : 0.f;
            }
        }
        float s = 0.f;
        #pragma unroll
        for (int st = 0; st < 4; ++st)
          #pragma unroll
          for (int ri = 0; ri < 4; ++ri) s += p[qg][st][ri];
        s += __shfl_xor(s, 16);
        s += __shfl_xor(s, 32);
        ls[qg] += s;

        #pragma unroll
        for (int st = 0; st < 4; ++st) {
          uint2 u2;
          u2.x = pk2bf(p[qg][st][0], p[qg][st][1]);
          u2.y = pk2bf(p[qg][st][2], p[qg][st][3]);
          *(uint2*)(&Plds[w][qg * 16 + lr][st * 16 + g * 4]) = u2;
        }
      }
    }

    if (more) { WAIT_VM(0); MEMBAR(); }
    WAIT_LGKM0(); MEMBAR();
    SBAR(); MEMBAR();
    if (more) WRITE_V(nxt);

    if (active) {
      short8 pf[2][2];
      #pragma unroll
      for (int qg = 0; qg < 2; ++qg) {
        pf[qg][0] = *(const short8*)(&Plds[w][qg * 16 + lr][g * 8]);
        pf[qg][1] = *(const short8*)(&Plds[w][qg * 16 + lr][32 + g * 8]);
      }
      __builtin_amdgcn_s_setprio(1);
      #pragma unroll
      for (int dt = 0; dt < 4; ++dt) {
        short8 vf0 = *(const short8*)(&Vt[cur][dt * 16 + lr][g * 8]);
        short8 vf1 = *(const short8*)(&Vt[cur][dt * 16 + lr][32 + g * 8]);
        accO[0][dt] = __builtin_amdgcn_mfma_f32_16x16x32_bf16(pf[0][0], vf0, accO[0][dt], 0, 0, 0);
        accO[1][dt] = __builtin_amdgcn_mfma_f32_16x16x32_bf16(pf[1][0], vf0, accO[1][dt], 0, 0, 0);
        accO[0][dt] = __builtin_amdgcn_mfma_f32_16x16x32_bf16(pf[0][1], vf1, accO[0][dt], 0, 0, 0);
        accO[1][dt] = __builtin_amdgcn_mfma_f32_16x16x32_bf16(pf[1][1], vf1, accO[1][dt], 0, 0, 0);
      }
      __builtin_amdgcn_s_setprio(0);
    }
    cur = nxt;
  }

  #pragma unroll
  for (int qg = 0; qg < 2; ++qg) {
    float lsq[4];
    #pragma unroll
    for (int ri = 0; ri < 4; ++ri) lsq[ri] = __shfl(ls[qg], g * 4 + ri);
    #pragma unroll
    for (int dt = 0; dt < 4; ++dt)
      #pragma unroll
      for (int ri = 0; ri < 4; ++ri) {
        int qi = qw + qg * 16 + g * 4 + ri;
        O[(size_t)(b * S + qi) * 1024 + h * 64 + dt * 16 + lr] = f2bf(accO[qg][dt][ri] / lsq[ri]);
      }
  }
}

// ---------------- launch ----------------
extern "C" void kernel_launch(void* const* d_in, const int* in_sizes, int n_in,
                              void* d_out, int out_size, void* d_ws, size_t ws_size,
                              hipStream_t stream) {
  const float* x  = (const float*)d_in[0];
  const float* Wq = (const float*)d_in[1];
  const float* Wk = (const float*)d_in[2];
  const float* Wv = (const float*)d_in[3];
  const float* Wo = (const float*)d_in[4];

  char* ws = (char*)d_ws;
  u16* xb   = (u16*)(ws);                    //  8 MiB: x bf16 [4096][1024]
  u16* Wcat = (u16*)(ws + (8  << 20));       //  6 MiB: [Wq;Wk;Wv] bf16 [3072][1024]
  u16* Wob  = (u16*)(ws + (14 << 20));       //  2 MiB: Wo bf16 [1024][1024]
  u16* QKV  = (u16*)(ws + (16 << 20));       // 24 MiB: [4096][3072]
  u16* Oatt = (u16*)(ws + (40 << 20));       //  8 MiB: [4096][1024]

  cvt_all<<<8192, 256, 0, stream>>>(x, Wq, Wk, Wv, Wo, xb, Wcat, Wob);
  gemm_t<128, 192, 1><<<512, 256, 0, stream>>>(xb, Wcat, QKV, 3072, 1024, 16);
  attn_swa<<<dim3(16, 32), 256, 0, stream>>>(QKV, Oatt);
  gemm_t<64, 128, 0><<<512, 256, 0, stream>>>(Oatt, Wob, d_out, 1024, 1024, 8);
}

// Round 17
// 82.574 us; speedup vs baseline: 1.2764x; 1.0152x over previous
//
#include <hip/hip_runtime.h>
#include <cstdint>

typedef uint16_t u16;
typedef __attribute__((ext_vector_type(8))) short short8;
typedef __attribute__((ext_vector_type(4))) float f32x4;

__device__ __forceinline__ u16 f2bf(float f) {
  uint32_t u = __float_as_uint(f);
  u += 0x7fff + ((u >> 16) & 1);   // RNE
  return (u16)(u >> 16);
}
__device__ __forceinline__ uint32_t pk2bf(float a, float b) {
  uint32_t ua = __float_as_uint(a) + 0x8000u;
  uint32_t ub = __float_as_uint(b) + 0x8000u;
  return (ua >> 16) | (ub & 0xFFFF0000u);
}

#define GLL16(gp, lp) __builtin_amdgcn_global_load_lds( \
    (__attribute__((address_space(1))) void*)(gp), \
    (__attribute__((address_space(3))) void*)(lp), 16, 0, 0)

#define SBAR()       __builtin_amdgcn_s_barrier()
#define WAIT_LGKM0() asm volatile("s_waitcnt lgkmcnt(0)" ::: "memory")
#define WAIT_VM(N)   asm volatile("s_waitcnt vmcnt(" #N ")" ::: "memory")
#define MEMBAR()     asm volatile("" ::: "memory")

// vmcnt immediate must be a literal in the asm string -> if constexpr dispatch
template<int N> __device__ __forceinline__ void wait_vm() {
  static_assert(N == 0 || N == 4 || N == 6 || N == 8 || N == 10 || N == 12, "add literal case");
  if constexpr (N == 0)  { WAIT_VM(0); }
  else if constexpr (N == 4)  { WAIT_VM(4); }
  else if constexpr (N == 6)  { WAIT_VM(6); }
  else if constexpr (N == 8)  { WAIT_VM(8); }
  else if constexpr (N == 10) { WAIT_VM(10); }
  else if constexpr (N == 12) { WAIT_VM(12); }
}

// ---------------- fused f32 -> bf16 convert; Wq pre-scaled by d^-0.5 * log2(e) ----------------
__global__ void cvt_all(const float* __restrict__ x,  const float* __restrict__ wq,
                        const float* __restrict__ wk, const float* __restrict__ wv,
                        const float* __restrict__ wo,
                        u16* __restrict__ xb, u16* __restrict__ wcat, u16* __restrict__ wob) {
  int i = blockIdx.x * 256 + threadIdx.x;
  const float4* src; ushort4* dst; int off; float sc = 1.0f;
  if (i < 1048576)      { src = (const float4*)x;  dst = (ushort4*)xb;              off = i; }
  else if (i < 1310720) { src = (const float4*)wq; dst = (ushort4*)wcat;            off = i - 1048576;
                          sc = 0.18033688011112042f; }   // 0.125 * log2(e)
  else if (i < 1572864) { src = (const float4*)wk; dst = (ushort4*)wcat + 262144;   off = i - 1310720; }
  else if (i < 1835008) { src = (const float4*)wv; dst = (ushort4*)wcat + 524288;   off = i - 1572864; }
  else                  { src = (const float4*)wo; dst = (ushort4*)wob;             off = i - 1835008; }
  float4 v = src[off];
  ushort4 o;
  o.x = f2bf(v.x * sc); o.y = f2bf(v.y * sc); o.z = f2bf(v.z * sc); o.w = f2bf(v.w * sc);
  dst[off] = o;
}

// ---------------- BMxBN counted-vmcnt GEMM (unchanged from round 16) ----------------
template<int BM, int BN, int OUT_BF16>
__global__ __launch_bounds__(256, 2) void gemm_t(const u16* __restrict__ A,
                                                 const u16* __restrict__ B,
                                                 void* __restrict__ Cout,
                                                 int N, int K, int ntN) {
  constexpr int MF = BM / 32;
  constexpr int NF = BN / 32;
  constexpr int G  = (BM + BN) / 32;
  __shared__ u16 smA[2][BM * 64];
  __shared__ u16 smB[2][BN * 64];
  const int tid  = threadIdx.x;
  const int lane = tid & 63, w = tid >> 6;
  const int wr = w >> 1, wc = w & 1;
  const int g = lane >> 4, lr = lane & 15;

  const int cpx = gridDim.x >> 3;
  const int id  = blockIdx.x;
  const int sw  = (id & 7) * cpx + (id >> 3);
  const int row0 = (sw / ntN) * BM, col0 = (sw % ntN) * BN;
  const int T = K >> 6;

  f32x4 acc[MF][NF];
  #pragma unroll
  for (int i = 0; i < MF; ++i)
    #pragma unroll
    for (int j = 0; j < NF; ++j) acc[i][j] = (f32x4){0.f, 0.f, 0.f, 0.f};

  auto STAGE = [&](int kt, int bufi) {
    #pragma unroll
    for (int j = 0; j < BM / 32; ++j) {
      int r  = j * 32 + w * 8 + (lane >> 3);
      int sb = ((lane & 7) << 4) ^ ((r & 7) << 4);
      GLL16(A + (size_t)(row0 + r) * K + kt * 64 + (sb >> 1),
            &smA[bufi][(size_t)(j * 32 + w * 8) * 64]);
    }
    #pragma unroll
    for (int j = 0; j < BN / 32; ++j) {
      int r  = j * 32 + w * 8 + (lane >> 3);
      int sb = ((lane & 7) << 4) ^ ((r & 7) << 4);
      GLL16(B + (size_t)(col0 + r) * K + kt * 64 + (sb >> 1),
            &smB[bufi][(size_t)(j * 32 + w * 8) * 64]);
    }
  };

  STAGE(0, 0); STAGE(1, 1);
  wait_vm<G>(); SBAR(); MEMBAR();

  for (int t = 0; t < T; ++t) {
    const int cur = t & 1;
    short8 a[MF][2], b[NF][2];
    #pragma unroll
    for (int mm = 0; mm < MF; ++mm)
      #pragma unroll
      for (int kh = 0; kh < 2; ++kh) {
        int row = wr * (BM / 2) + mm * 16 + lr;
        int col = (kh * 64 + g * 16) ^ ((row & 7) << 4);
        a[mm][kh] = *(const short8*)((const char*)&smA[cur][0] + row * 128 + col);
      }
    #pragma unroll
    for (int nn = 0; nn < NF; ++nn)
      #pragma unroll
      for (int kh = 0; kh < 2; ++kh) {
        int row = wc * (BN / 2) + nn * 16 + lr;
        int col = (kh * 64 + g * 16) ^ ((row & 7) << 4);
        b[nn][kh] = *(const short8*)((const char*)&smB[cur][0] + row * 128 + col);
      }
    WAIT_LGKM0(); MEMBAR(); SBAR(); MEMBAR();

    if (t + 2 < T) STAGE(t + 2, cur);

    __builtin_amdgcn_s_setprio(1);
    #pragma unroll
    for (int kh = 0; kh < 2; ++kh)
      #pragma unroll
      for (int mm = 0; mm < MF; ++mm)
        #pragma unroll
        for (int nn = 0; nn < NF; ++nn)
          acc[mm][nn] = __builtin_amdgcn_mfma_f32_16x16x32_bf16(
              a[mm][kh], b[nn][kh], acc[mm][nn], 0, 0, 0);
    __builtin_amdgcn_s_setprio(0);

    if (t + 1 < T) {
      if (t + 2 < T) { wait_vm<G>(); } else { wait_vm<0>(); }
      SBAR(); MEMBAR();
    }
  }

  #pragma unroll
  for (int i = 0; i < MF; ++i)
    #pragma unroll
    for (int j = 0; j < NF; ++j)
      #pragma unroll
      for (int ri = 0; ri < 4; ++ri) {
        int rr = row0 + wr * (BM / 2) + i * 16 + g * 4 + ri;
        int cc = col0 + wc * (BN / 2) + j * 16 + lr;
        if (OUT_BF16) ((u16*)Cout)[(size_t)rr * N + cc] = f2bf(acc[i][j][ri]);
        else          ((float*)Cout)[(size_t)rr * N + cc] = acc[i][j][ri];
      }
}

// ---------------- Flash sliding-window attention (v9: 8 waves x 16 queries) ----------------
// Block = 512 thr = 8 waves; block = (b, h, 128 queries); wave owns 16 queries (1 qg).
// Same round-12 schedule (barrier before PV, per-wave tile skip); per-wave work halves,
// resident waves/CU double (8 -> 16, 4/SIMD). LDS 53,248 B -> 2 blocks/CU.
__global__ __launch_bounds__(512, 4) void attn_swa(const u16* __restrict__ QKV, u16* __restrict__ O) {
  const int S = 2048;
  const int qb = blockIdx.x * 128;
  const int b = blockIdx.y >> 4, h = blockIdx.y & 15;
  const int tid = threadIdx.x;
  const int lane = tid & 63, w = tid >> 6;           // w in 0..7
  const int g = lane >> 4, lr = lane & 15;

  __shared__ u16 Klds[2][64 * 64];   // [64 keys][64 d], rows 128B, byte ^= (row&7)<<4
  __shared__ u16 Vt[2][64][72];      // V^T [d][key], pitch 144B, double-buffered
  __shared__ u16 Plds[8][16][72];    // per-wave P^T [q 0..15][key 0..63], pitch 144B

  const u16* Qb = QKV + (size_t)b * S * 3072 + h * 64;
  const u16* Kb = QKV + (size_t)b * S * 3072 + 1024 + h * 64;
  const u16* Vb = QKV + (size_t)b * S * 3072 + 2048 + h * 64;

  const int qw = qb + w * 16;
  short8 qf[2];
  #pragma unroll
  for (int kh = 0; kh < 2; ++kh)
    qf[kh] = *(const short8*)(Qb + (size_t)(qw + lr) * 3072 + kh * 32 + g * 8);

  float ls = 0.f;
  f32x4 accO[4];
  #pragma unroll
  for (int i = 0; i < 4; ++i) accO[i] = (f32x4){0.f, 0.f, 0.f, 0.f};

  int ks = qb - 511; if (ks < 0) ks = 0; ks &= ~63;
  const int ke = qb + 127;
  const int nt = ((ke - ks) >> 6) + 1;

  short8 vreg;   // V in flight: key = lane, d = w*8 .. w*8+7

  auto STAGE_K = [&](int kb, int buf) {
    int r  = w * 8 + (lane >> 3);                    // 8 waves x 8 rows = 64 keys
    int sb = ((lane & 7) << 4) ^ ((r & 7) << 4);
    const u16* gp = Kb + (size_t)(kb + r) * 3072 + (sb >> 1);
    u16* lp = Klds[buf] + w * 512;                   // wave-uniform base (8 rows x 128B)
    GLL16(gp, lp);
  };
  auto LOAD_V = [&](int kb) {
    vreg = *(const short8*)(Vb + (size_t)(kb + lane) * 3072 + w * 8);
  };
  auto WRITE_V = [&](int buf) {
    #pragma unroll
    for (int j = 0; j < 8; ++j) Vt[buf][w * 8 + j][lane] = (u16)vreg[j];
  };

  // prologue: stage tile 0; publish Klds[0]; Vt[0] written post-barrier (published at B0)
  LOAD_V(ks); MEMBAR();
  STAGE_K(ks, 0); MEMBAR();
  WAIT_VM(0); MEMBAR();
  SBAR(); MEMBAR();
  WRITE_V(0);

  int cur = 0, kb = ks;
  for (int t = 0; t < nt; ++t, kb += 64) {
    const int nxt = cur ^ 1;
    const bool more = (t + 1 < nt);
    if (more) { LOAD_V(kb + 64); MEMBAR(); STAGE_K(kb + 64, nxt); MEMBAR(); }

    // per-wave compute skip: tile outside [qw-511, qw+15] contributes only masked zeros
    const bool active = (kb <= qw + 15) && (kb + 63 >= qw - 511);
    if (active) {
      // ---- QK^T (swapped): 4 key-subtiles x 2 MFMAs over d=64 ----
      float p[4][4];
      #pragma unroll
      for (int st = 0; st < 4; ++st) {
        f32x4 c4 = (f32x4){0.f, 0.f, 0.f, 0.f};
        int r = st * 16 + lr;
        int swz = (r & 7) << 4;
        const char* krow = (const char*)(Klds[cur]) + r * 128;
        short8 kf0 = *(const short8*)(krow + ((g * 16) ^ swz));
        short8 kf1 = *(const short8*)(krow + ((64 + g * 16) ^ swz));
        __builtin_amdgcn_s_setprio(1);
        c4 = __builtin_amdgcn_mfma_f32_16x16x32_bf16(kf0, qf[0], c4, 0, 0, 0);
        c4 = __builtin_amdgcn_mfma_f32_16x16x32_bf16(kf1, qf[1], c4, 0, 0, 0);
        __builtin_amdgcn_s_setprio(0);
        #pragma unroll
        for (int ri = 0; ri < 4; ++ri) p[st][ri] = c4[ri];
      }

      // ---- exp2 + mask (clean fast path) + row sum + P^T -> LDS ----
      const bool clean = (kb + 63 <= qw) && (qw + 15 - kb < 512);
      if (clean) {
        #pragma unroll
        for (int st = 0; st < 4; ++st)
          #pragma unroll
          for (int ri = 0; ri < 4; ++ri)
            p[st][ri] = __builtin_amdgcn_exp2f(p[st][ri]);
      } else {
        const int base = qw + lr - kb;
        #pragma unroll
        for (int st = 0; st < 4; ++st)
          #pragma unroll
          for (int ri = 0; ri < 4; ++ri) {
            float e = __builtin_amdgcn_exp2f(p[st][ri]);
            p[st][ri] = ((uint32_t)(base - (st * 16 + g * 4 + ri)) < 512u) ? e : 0.f;
          }
      }
      {
        float s = 0.f;
        #pragma unroll
        for (int st = 0; st < 4; ++st)
          #pragma unroll
          for (int ri = 0; ri < 4; ++ri) s += p[st][ri];
        s += __shfl_xor(s, 16);
        s += __shfl_xor(s, 32);
        ls += s;
      }
      #pragma unroll
      for (int st = 0; st < 4; ++st) {
        uint2 u2;
        u2.x = pk2bf(p[st][0], p[st][1]);
        u2.y = pk2bf(p[st][2], p[st][3]);
        *(uint2*)(&Plds[w][lr][st * 16 + g * 4]) = u2;
      }
    }

    // ---- mid-tile sync: K(t+1)+V(t+1) landed + own ds ops drained -> ONE barrier ----
    if (more) { WAIT_VM(0); MEMBAR(); }
    WAIT_LGKM0(); MEMBAR();
    SBAR(); MEMBAR();            // publishes Klds[nxt], Vt[cur] (prev iter), Plds
    if (more) WRITE_V(nxt);      // post-barrier: touches only Vt[nxt]

    if (active) {
      // ---- PV: A = P^T, B = V^T[cur] ----
      short8 pf0 = *(const short8*)(&Plds[w][lr][g * 8]);
      short8 pf1 = *(const short8*)(&Plds[w][lr][32 + g * 8]);
      __builtin_amdgcn_s_setprio(1);
      #pragma unroll
      for (int dt = 0; dt < 4; ++dt) {
        short8 vf0 = *(const short8*)(&Vt[cur][dt * 16 + lr][g * 8]);
        short8 vf1 = *(const short8*)(&Vt[cur][dt * 16 + lr][32 + g * 8]);
        accO[dt] = __builtin_amdgcn_mfma_f32_16x16x32_bf16(pf0, vf0, accO[dt], 0, 0, 0);
        accO[dt] = __builtin_amdgcn_mfma_f32_16x16x32_bf16(pf1, vf1, accO[dt], 0, 0, 0);
      }
      __builtin_amdgcn_s_setprio(0);
    }
    cur = nxt;
  }

  float lsq[4];
  #pragma unroll
  for (int ri = 0; ri < 4; ++ri) lsq[ri] = __shfl(ls, g * 4 + ri);
  #pragma unroll
  for (int dt = 0; dt < 4; ++dt)
    #pragma unroll
    for (int ri = 0; ri < 4; ++ri) {
      int qi = qw + g * 4 + ri;
      O[(size_t)(b * S + qi) * 1024 + h * 64 + dt * 16 + lr] = f2bf(accO[dt][ri] / lsq[ri]);
    }
}

// ---------------- launch ----------------
extern "C" void kernel_launch(void* const* d_in, const int* in_sizes, int n_in,
                              void* d_out, int out_size, void* d_ws, size_t ws_size,
                              hipStream_t stream) {
  const float* x  = (const float*)d_in[0];
  const float* Wq = (const float*)d_in[1];
  const float* Wk = (const float*)d_in[2];
  const float* Wv = (const float*)d_in[3];
  const float* Wo = (const float*)d_in[4];

  char* ws = (char*)d_ws;
  u16* xb   = (u16*)(ws);                    //  8 MiB: x bf16 [4096][1024]
  u16* Wcat = (u16*)(ws + (8  << 20));       //  6 MiB: [Wq;Wk;Wv] bf16 [3072][1024]
  u16* Wob  = (u16*)(ws + (14 << 20));       //  2 MiB: Wo bf16 [1024][1024]
  u16* QKV  = (u16*)(ws + (16 << 20));       // 24 MiB: [4096][3072]
  u16* Oatt = (u16*)(ws + (40 << 20));       //  8 MiB: [4096][1024]

  cvt_all<<<8192, 256, 0, stream>>>(x, Wq, Wk, Wv, Wo, xb, Wcat, Wob);
  gemm_t<128, 192, 1><<<512, 256, 0, stream>>>(xb, Wcat, QKV, 3072, 1024, 16);
  attn_swa<<<dim3(16, 32), 512, 0, stream>>>(QKV, Oatt);
  gemm_t<64, 128, 0><<<512, 256, 0, stream>>>(Oatt, Wob, d_out, 1024, 1024, 8);
}